// Round 4
// baseline (1639.858 us; speedup 1.0000x reference)
//
#include <hip/hip_runtime.h>
#include <math.h>

#define EPS 1e-5f
#define BNB 1e-4f
#define GMAX 16

typedef __attribute__((ext_vector_type(8))) short short8;
typedef __attribute__((ext_vector_type(4))) float f32x4;
typedef __attribute__((ext_vector_type(4))) unsigned short ushort4_t;

static __device__ __forceinline__ void atomAdd(float* p, float v) { unsafeAtomicAdd(p, v); }

static __device__ __forceinline__ unsigned short f2bf(float f) {
  unsigned u = __float_as_uint(f);
  unsigned r = (u + 0x7fffu + ((u >> 16) & 1u)) >> 16;
  return (unsigned short)r;
}
static __device__ __forceinline__ float bflo(unsigned u) { return __uint_as_float(u << 16); }
static __device__ __forceinline__ float bfhi(unsigned u) { return __uint_as_float(u & 0xffff0000u); }

// ---------------- column stats over N x 128 ----------------
__global__ void k_stats(const float* __restrict__ X, int R, float* __restrict__ st)
{
  const int C = 128;
  int T = gridDim.x * blockDim.x;
  int t = blockIdx.x * blockDim.x + threadIdx.x;
  int c = t % C, r0 = t / C, rsr = T / C;
  float s = 0.f, s2 = 0.f;
  for (int r = r0; r < R; r += rsr) {
    float v = X[(size_t)r * C + c];
    s += v; s2 += v * v;
  }
  atomAdd(&st[c], s);
  atomAdd(&st[C + c], s2);
}

// fused stats for xc = na*h and xo = (1-na)*h
__global__ void k_stats2(const float* __restrict__ X, int R,
                         float* __restrict__ stA, float* __restrict__ stB,
                         const float* __restrict__ na)
{
  const int C = 128;
  int T = gridDim.x * blockDim.x;
  int t = blockIdx.x * blockDim.x + threadIdx.x;
  int c = t % C, r0 = t / C, rsr = T / C;
  float sa = 0, sa2 = 0, sb = 0, sb2 = 0;
  for (int r = r0; r < R; r += rsr) {
    float v = X[(size_t)r * C + c];
    float a = na[r] * v;
    float b = (1.f - na[r]) * v;
    sa += a; sa2 += a * a; sb += b; sb2 += b * b;
  }
  atomAdd(&stA[c], sa); atomAdd(&stA[C + c], sa2);
  atomAdd(&stB[c], sb); atomAdd(&stB[C + c], sb2);
}

// st layout: [0,C) sum, [C,2C) sumsq, [2C,3C) mean, [3C,4C) inv; rezeroes sums.
__global__ void k_finN(float* s0, int R0, float* s1, int R1, float* s2, int R2)
{
  int z = blockIdx.x;
  float* st = z == 0 ? s0 : (z == 1 ? s1 : s2);
  int R = z == 0 ? R0 : (z == 1 ? R1 : R2);
  const int C = 128;
  int c = threadIdx.x;
  if (c < C) {
    float m = st[c] / R;
    float v = st[C + c] / R - m * m;
    st[2 * C + c] = m;
    st[3 * C + c] = rsqrtf(v + EPS);
    st[c] = 0.f; st[C + c] = 0.f;
  }
}

// ---------------- weight prep: 6 matrices -> bf16 transposed+swizzled ----------------
__global__ void k_prepW6(const float* __restrict__ W_feat, const float* __restrict__ convW,
                         const float* __restrict__ xcW, const float* __restrict__ xoW,
                         unsigned short* __restrict__ Wt)
{
  int idx = blockIdx.x * 256 + threadIdx.x;  // 6*16384
  int which = idx >> 14, e = idx & 16383;
  const float* W = which == 0 ? W_feat
                 : (which <= 3 ? convW + (size_t)(which - 1) * 16384
                 : (which == 4 ? xcW : xoW));
  int n = e >> 7, k = e & 127;
  Wt[((size_t)which << 14) + (n << 7) + (((k >> 3) ^ (n & 7)) << 3) + (k & 7)] = f2bf(W[k * 128 + n]);
}

// ---------------- MFMA matmul: Out = act( BN(scale*A) @ W ) ----------------
template<int ACT, int OUTBF16, int STATS>
__global__ __launch_bounds__(256) void k_mm_mfma(
    const float* __restrict__ A, const float* __restrict__ st,
    const unsigned short* __restrict__ Wt, void* __restrict__ OutV,
    int Nrows, int scale_mode, const float* __restrict__ na,
    float* __restrict__ stOut)
{
  __shared__ unsigned short sA[64 * 128];
  __shared__ unsigned short sW[128 * 128];
  int t = threadIdx.x;
  int r0 = blockIdx.x * 64;
  {
    const short8* src = (const short8*)Wt;
    short8* dst = (short8*)sW;
    #pragma unroll
    for (int j = 0; j < 8; j++) dst[t + 256 * j] = src[t + 256 * j];
  }
  {
    int r = t >> 2;
    int rg = r0 + r;
    bool valid = rg < Nrows;
    float sc = 1.f;
    if (scale_mode == 1) sc = valid ? na[rg] : 0.f;
    else if (scale_mode == 2) sc = valid ? (1.f - na[rg]) : 0.f;
    #pragma unroll
    for (int i = 0; i < 8; i++) {
      int k = ((t & 3) << 2) + (i << 4);
      float4 va = valid ? *(const float4*)(A + (size_t)rg * 128 + k)
                        : make_float4(0.f, 0.f, 0.f, 0.f);
      float4 mm = *(const float4*)(st + 256 + k);
      float4 iv = *(const float4*)(st + 384 + k);
      ushort4_t w;
      w.x = f2bf((sc * va.x - mm.x) * iv.x + BNB);
      w.y = f2bf((sc * va.y - mm.y) * iv.y + BNB);
      w.z = f2bf((sc * va.z - mm.z) * iv.z + BNB);
      w.w = f2bf((sc * va.w - mm.w) * iv.w + BNB);
      *(ushort4_t*)(&sA[(r << 7) + (((k >> 3) ^ (r & 7)) << 3) + (k & 7)]) = w;
    }
  }
  __syncthreads();

  int w = t >> 6, l = t & 63;
  int n0 = w * 32;
  int la = l & 15, hi = l >> 4;
  f32x4 acc[4][2];
  #pragma unroll
  for (int m = 0; m < 4; m++)
    #pragma unroll
    for (int nf = 0; nf < 2; nf++) {
      acc[m][nf][0] = 0.f; acc[m][nf][1] = 0.f;
      acc[m][nf][2] = 0.f; acc[m][nf][3] = 0.f;
    }
  #pragma unroll
  for (int ks = 0; ks < 4; ks++) {
    int slot = ks * 4 + hi;
    short8 af[4], bfr[2];
    #pragma unroll
    for (int m = 0; m < 4; m++) {
      int r = 16 * m + la;
      af[m] = *(const short8*)(&sA[(r << 7) + ((slot ^ (r & 7)) << 3)]);
    }
    #pragma unroll
    for (int nf = 0; nf < 2; nf++) {
      int n = n0 + 16 * nf + la;
      bfr[nf] = *(const short8*)(&sW[(n << 7) + ((slot ^ (n & 7)) << 3)]);
    }
    #pragma unroll
    for (int m = 0; m < 4; m++)
      #pragma unroll
      for (int nf = 0; nf < 2; nf++)
        acc[m][nf] = __builtin_amdgcn_mfma_f32_16x16x32_bf16(af[m], bfr[nf], acc[m][nf], 0, 0, 0);
  }
  #pragma unroll
  for (int nf = 0; nf < 2; nf++) {
    int c = n0 + 16 * nf + la;
    float scol = 0.f, qcol = 0.f;
    #pragma unroll
    for (int m = 0; m < 4; m++) {
      #pragma unroll
      for (int q = 0; q < 4; q++) {
        int r = r0 + 16 * m + hi * 4 + q;
        float v = acc[m][nf][q];
        if (ACT == 1) v = fmaxf(v, 0.f);
        if (r < Nrows) {
          if (OUTBF16) ((unsigned short*)OutV)[(size_t)r * 128 + c] = f2bf(v);
          else         ((float*)OutV)[(size_t)r * 128 + c] = v;
          if (STATS) { scol += v; qcol += v * v; }
        }
      }
    }
    if (STATS) {
      scol += __shfl_xor(scol, 16); scol += __shfl_xor(scol, 32);
      qcol += __shfl_xor(qcol, 16); qcol += __shfl_xor(qcol, 32);
      if (hi == 0) { atomAdd(&stOut[c], scol); atomAdd(&stOut[128 + c], qcol); }
    }
  }
}

// ---------------- graph structure ----------------
__global__ void k_hist(const int* __restrict__ src, const int* __restrict__ dst, int E,
                       float* __restrict__ degF, int* __restrict__ cnt)
{
  int e = blockIdx.x * blockDim.x + threadIdx.x;
  if (e < E) {
    atomAdd(&degF[src[e]], 1.f);
    atomicAdd(&cnt[dst[e]], 1);
  }
}
__global__ void k_rsqrt1(const float* __restrict__ deg, float* __restrict__ dis,
                         float* __restrict__ dis2, int Nn)
{
  int i = blockIdx.x * blockDim.x + threadIdx.x;
  if (i < Nn) {
    float d = rsqrtf(deg[i] + 1.f);
    dis[i] = d;
    dis2[i] = d * d;
  }
}
// exclusive scan over (cnt[i] + 1); zeroes cnt for reuse
__global__ void k_scan(int* __restrict__ cnt, int Nn, int* __restrict__ row_start)
{
  __shared__ int sd[1024];
  __shared__ int srun;
  int t = threadIdx.x;
  if (t == 0) srun = 0;
  __syncthreads();
  for (int base = 0; base < Nn; base += 1024) {
    int v = 0;
    if (base + t < Nn) { v = cnt[base + t] + 1; cnt[base + t] = 0; }
    sd[t] = v;
    __syncthreads();
    for (int off = 1; off < 1024; off <<= 1) {
      int x = (t >= off) ? sd[t - off] : 0;
      __syncthreads();
      sd[t] += x;
      __syncthreads();
    }
    int incl = sd[t];
    int run = srun;
    if (base + t < Nn) row_start[base + t] = run + incl - v;
    __syncthreads();
    if (t == 1023) srun = run + incl;
    __syncthreads();
  }
  if (t == 0) row_start[Nn] = srun;
}
// fill CSR: data edges at slot 1+, self at slot 0
__global__ void k_fillB(const int* __restrict__ src, const int* __restrict__ dst, int E, int Nn,
                        const int* __restrict__ row_start, int* __restrict__ cnt,
                        const float* __restrict__ dis, const float* __restrict__ dis2,
                        int2* __restrict__ icP, int* __restrict__ edgepos)
{
  int e = blockIdx.x * blockDim.x + threadIdx.x;
  if (e < E) {
    int d = dst[e], s = src[e];
    int k = atomicAdd(&cnt[d], 1);
    int pos = row_start[d] + 1 + k;
    icP[pos] = make_int2(s, __float_as_int(dis[s] * dis[d]));
    edgepos[e] = pos;
  } else if (e < E + Nn) {
    int i = e - E;
    icP[row_start[i]] = make_int2(i, __float_as_int(dis2[i]));
  }
}
// slot-balanced wave ranges: wstart[w] = lower_bound(rs, w*spw)
__global__ void k_wstart(const int* __restrict__ rs, int Nn, int S, int nw,
                         int* __restrict__ wst)
{
  int w = blockIdx.x * blockDim.x + threadIdx.x;
  if (w > nw) return;
  long long target = (long long)w * ((S + nw - 1) / nw);
  int lo = 0, hi = Nn;
  while (lo < hi) {
    int mid = (lo + hi) >> 1;
    if ((long long)rs[mid] < target) lo = mid + 1; else hi = mid;
  }
  wst[w] = lo;
}

// ---------------- gather: padded-group stream, 2-deep pipeline, work stealing ----------------
template<int MODE>  // 0: relu+out+stats, 1: relu+out, 2: elu+pool (fused dual-set)
__global__ __launch_bounds__(256) void k_gath(
    const unsigned short* __restrict__ Hb0, const int2* __restrict__ ic0,
    const float* __restrict__ bias0, float* __restrict__ Out,
    const unsigned short* __restrict__ Hb1, const int2* __restrict__ ic1,
    const float* __restrict__ bias1, float* __restrict__ outg1,
    float* __restrict__ outg0,
    const int* __restrict__ rs, const int* __restrict__ wstart, int nw,
    const int* __restrict__ batch, int* __restrict__ ctr,
    float* __restrict__ st)
{
  __shared__ int2 sWin[4][128];
  __shared__ int  sGM[4][GMAX];
  __shared__ int  sBT[4][20];

  int t = threadIdx.x, lane = t & 63, wslot = t >> 6;
  int c0 = lane * 2;

  const unsigned short* Hb = Hb0;
  const int2* ic = ic0;
  const float* bias = bias0;
  float* outg = outg0;
  int* myctr = ctr;
  if (MODE == 2) {
    int half = gridDim.x >> 1;
    if ((int)blockIdx.x >= half) { Hb = Hb1; ic = ic1; bias = bias1; outg = outg1; myctr = ctr + 1; }
  }

  float b0 = bias[c0], b1 = bias[c0 + 1];
  float s0 = 0, s1 = 0, q0 = 0, q1 = 0;
  int curg = -1; float gx = 0.f, gy = 0.f;

  for (;;) {
    int w = 0;
    if (lane == 0) w = atomicAdd(myctr, 1);
    w = __shfl(w, 0);
    if (w >= nw) break;
    int ci = wstart[w], ib = wstart[w + 1];
    if (ci >= ib) continue;

    int curnode = -1, curbatch = -1;
    float ax = 0.f, ay = 0.f;
    int p = 0;

    auto FLUSH = [&]() {
      if (curnode < 0) return;
      if (MODE < 2) {
        float fx = fmaxf(ax, 0.f), fy = fmaxf(ay, 0.f);
        *(float2*)(Out + (size_t)curnode * 128 + c0) = make_float2(fx, fy);
        if (MODE == 0) { s0 += fx; s1 += fy; q0 += fx * fx; q1 += fy * fy; }
      } else {
        float fx = ax > 0.f ? ax : expm1f(ax);
        float fy = ay > 0.f ? ay : expm1f(ay);
        if (curbatch != curg) {
          if (curg >= 0) {
            atomAdd(&outg[curg * 128 + c0], gx);
            atomAdd(&outg[curg * 128 + c0 + 1], gy);
          }
          curg = curbatch; gx = fx; gy = fy;
        } else { gx += fx; gy += fy; }
      }
    };

    while (ci < ib) {
      // ---- lane-parallel refill construction ----
      int nodechunk = min(ib - ci, 16);
      int bl = (lane <= nodechunk) ? rs[ci + lane] : 0;
      int bn = __shfl(bl, lane + 1);
      int len = bn - bl;
      int rem = (lane < nodechunk) ? len : 0;
      if (lane == 0 && nodechunk > 0) rem = len - p;
      int ng = (rem + 7) >> 3;
      int pre = ng;
      #pragma unroll
      for (int off = 1; off < 64; off <<= 1) {
        int x = __shfl_up(pre, off);
        if (lane >= off) pre += x;
      }
      int Gtot = __shfl(pre, 63);
      int Gw = min(Gtot, GMAX);
      int g0 = pre - ng;
      int startbase = bl + ((lane == 0) ? p : 0);
      for (int g = 0; g < ng; g++) {
        int gi = g0 + g;
        if (gi < Gw)
          sGM[wslot][gi] = (lane << 26) | ((startbase + (g << 3)) << 4) | min(8, rem - (g << 3));
      }
      if (MODE == 2 && lane < nodechunk) sBT[wslot][lane] = batch[ci + lane];
      unsigned long long fb = __ballot(lane < nodechunk && pre <= Gw);
      int nfull = __popcll(fb);
      int nI = ci + nfull, nP = 0;
      if (nfull < nodechunk) {
        int g0s = __shfl(g0, nfull);
        int cg = Gw - g0s; if (cg < 0) cg = 0;
        nP = ((nfull == 0) ? p : 0) + (cg << 3);
      }
      asm volatile("s_waitcnt lgkmcnt(0)" ::: "memory");
      __builtin_amdgcn_sched_barrier(0);
      // ---- copy slots to LDS (zero-padded groups) ----
      for (int idx = lane; idx < (Gw << 3); idx += 64) {
        int meta = sGM[wslot][idx >> 3];
        int stp = (meta >> 4) & 0x3FFFFF;
        int cntp = meta & 15;
        int q = idx & 7;
        int2 v = make_int2(0, 0);
        if (q < cntp) v = ic[stp + q];
        sWin[wslot][idx] = v;
      }
      asm volatile("s_waitcnt lgkmcnt(0)" ::: "memory");
      __builtin_amdgcn_sched_barrier(0);
      // ---- 2-deep pipelined processing ----
      float cfA[8], cfB[8];
      unsigned uA[8], uB[8];
      auto ISSUE = [&](int g, float* cf, unsigned* u) {
        #pragma unroll
        for (int q = 0; q < 8; q++) { cf[q] = 0.f; u[q] = 0u; }
        if (g < Gw) {
          #pragma unroll
          for (int q = 0; q < 8; q++) {
            int2 pr = sWin[wslot][(g << 3) + q];
            cf[q] = __int_as_float(pr.y);
            if (pr.y != 0)
              u[q] = *(const unsigned*)(Hb + (size_t)pr.x * 128 + c0);
          }
        }
      };
      auto CONSUME = [&](int g, float* cf, unsigned* u) {
        if (g < Gw) {
          int meta = sGM[wslot][g];
          int nd = meta >> 26;
          int ndg = ci + nd;
          if (ndg != curnode) {
            FLUSH();
            curnode = ndg;
            if (MODE == 2) curbatch = sBT[wslot][nd];
            ax = b0; ay = b1;
          }
          #pragma unroll
          for (int q = 0; q < 8; q++) {
            ax = fmaf(cf[q], bflo(u[q]), ax);
            ay = fmaf(cf[q], bfhi(u[q]), ay);
          }
        }
      };
      ISSUE(0, cfA, uA);
      for (int g = 0; g < Gw; g += 2) {
        ISSUE(g + 1, cfB, uB);
        CONSUME(g, cfA, uA);
        ISSUE(g + 2, cfA, uA);
        CONSUME(g + 1, cfB, uB);
      }
      ci = nI; p = nP;
    }
    FLUSH();
  }
  if (MODE == 2) {
    if (curg >= 0) {
      atomAdd(&outg[curg * 128 + c0], gx);
      atomAdd(&outg[curg * 128 + c0 + 1], gy);
    }
  }
  if (MODE == 0) {
    float* red = (float*)sWin;
    __syncthreads();
    red[t] = s0; red[256 + t] = s1; red[512 + t] = q0; red[768 + t] = q1;
    __syncthreads();
    if (t < 64) {
      float a0 = red[t] + red[t + 64] + red[t + 128] + red[t + 192];
      float a1 = red[256 + t] + red[256 + t + 64] + red[256 + t + 128] + red[256 + t + 192];
      float a2 = red[512 + t] + red[512 + t + 64] + red[512 + t + 128] + red[512 + t + 192];
      float a3 = red[768 + t] + red[768 + t + 64] + red[768 + t + 128] + red[768 + t + 192];
      atomAdd(&st[2 * t], a0); atomAdd(&st[2 * t + 1], a1);
      atomAdd(&st[128 + 2 * t], a2); atomAdd(&st[128 + 2 * t + 1], a3);
    }
  }
}

// ---------------- per-node projections P,Q + hn ----------------
__global__ __launch_bounds__(256) void k_pqhn(
    const float* __restrict__ H, const float* __restrict__ eW,
    const float* __restrict__ naW, float4* __restrict__ PQ,
    float2* __restrict__ hn, int Nn)
{
  __shared__ float w[128][6];
  int t = threadIdx.x;
  if (t < 128) {
    w[t][0] = eW[2 * t];       w[t][1] = eW[2 * t + 1];
    w[t][2] = eW[256 + 2 * t]; w[t][3] = eW[256 + 2 * t + 1];
    w[t][4] = naW[2 * t];      w[t][5] = naW[2 * t + 1];
  }
  __syncthreads();
  int lane = t & 63;
  int wid = (blockIdx.x * 256 + t) >> 6;
  int nwv = (gridDim.x * 256) >> 6;
  for (int i = wid; i < Nn; i += nwv) {
    const float2 h2 = *(const float2*)(H + (size_t)i * 128 + lane * 2);
    int k0 = lane * 2, k1 = lane * 2 + 1;
    float p0 = h2.x * w[k0][0] + h2.y * w[k1][0];
    float p1 = h2.x * w[k0][1] + h2.y * w[k1][1];
    float q0 = h2.x * w[k0][2] + h2.y * w[k1][2];
    float q1 = h2.x * w[k0][3] + h2.y * w[k1][3];
    float n0 = h2.x * w[k0][4] + h2.y * w[k1][4];
    float n1 = h2.x * w[k0][5] + h2.y * w[k1][5];
    #pragma unroll
    for (int o = 32; o > 0; o >>= 1) {
      p0 += __shfl_xor(p0, o); p1 += __shfl_xor(p1, o);
      q0 += __shfl_xor(q0, o); q1 += __shfl_xor(q1, o);
      n0 += __shfl_xor(n0, o); n1 += __shfl_xor(n1, o);
    }
    if (lane == 0) {
      PQ[i] = make_float4(p0, p1, q0, q1);
      hn[i] = make_float2(n0, n1);
    }
  }
}

// node-att propagate (2 channels; self edge in CSR)
__global__ void k_natt(const float2* __restrict__ hn,
                       const int* __restrict__ rs, const int2* __restrict__ icP,
                       const float* __restrict__ nab, float2* __restrict__ nlog, int Nn)
{
  int i = blockIdx.x * blockDim.x + threadIdx.x;
  if (i >= Nn) return;
  float a0 = nab[0], a1 = nab[1];
  int jb = rs[i], je = rs[i + 1];
  for (int j = jb; j < je; j++) {
    int2 v = icP[j];
    float c = __int_as_float(v.y);
    float2 hs = hn[v.x];
    a0 += c * hs.x;
    a1 += c * hs.y;
  }
  nlog[i] = make_float2(a0, a1);
}

// per-edge attention + weighted-degree accumulation
__global__ void k_edge(const int* __restrict__ src, const int* __restrict__ dst, int E,
                       const float4* __restrict__ PQ, const float* __restrict__ eb,
                       float* __restrict__ attE,
                       float* __restrict__ degc, float* __restrict__ dego)
{
  int e = blockIdx.x * blockDim.x + threadIdx.x;
  if (e >= E) return;
  int s = src[e], d = dst[e];
  float4 ps = PQ[s];
  float4 pd = PQ[d];
  float ld = (ps.x - ps.y) + (pd.z - pd.w) + (eb[0] - eb[1]);
  float att = 1.f / (1.f + expf(-ld));
  attE[e] = att;
  atomAdd(&degc[s], att);
  atomAdd(&dego[s], 1.f - att);
}

__global__ void k_nodefin(const float* __restrict__ degc, const float* __restrict__ dego,
                          const float2* __restrict__ nlog,
                          float* __restrict__ disc, float* __restrict__ diso,
                          float* __restrict__ selfcc, float* __restrict__ selfco,
                          float* __restrict__ na0, int Nn)
{
  int i = blockIdx.x * blockDim.x + threadIdx.x;
  if (i >= Nn) return;
  float dc = rsqrtf(degc[i] + 1.f);
  float dd = rsqrtf(dego[i] + 1.f);
  disc[i] = dc; diso[i] = dd;
  selfcc[i] = dc * dc; selfco[i] = dd * dd;
  float2 l = nlog[i];
  na0[i] = 1.f / (1.f + expf(-(l.x - l.y)));
}

// weighted (idx,coef) pairs into CSR order (edges + self)
__global__ void k_edge2B(const int* __restrict__ src, const int* __restrict__ dst, int E, int Nn,
                         const float* __restrict__ attE, const int* __restrict__ edgepos,
                         const int* __restrict__ rs,
                         const float* __restrict__ disc, const float* __restrict__ diso,
                         const float* __restrict__ selfcc, const float* __restrict__ selfco,
                         int2* __restrict__ icC, int2* __restrict__ icO)
{
  int e = blockIdx.x * blockDim.x + threadIdx.x;
  if (e < E) {
    int s = src[e], d = dst[e];
    int pos = edgepos[e];
    float att = attE[e];
    icC[pos] = make_int2(s, __float_as_int(disc[s] * att * disc[d]));
    icO[pos] = make_int2(s, __float_as_int(diso[s] * (1.f - att) * diso[d]));
  } else if (e < E + Nn) {
    int i = e - E;
    int pp = rs[i];
    icC[pp] = make_int2(i, __float_as_int(selfcc[i]));
    icO[pp] = make_int2(i, __float_as_int(selfco[i]));
  }
}

// ---------------- heads ----------------
// batched first-layer head MM: z=0 C(relu), z=1 O(relu), z=2 CO(double elu, K=256 via stat pair)
__global__ void k_heads1(const float* __restrict__ xc_g, const float* __restrict__ xo_g,
                         const float* __restrict__ stC, const float* __restrict__ stO,
                         const float* __restrict__ cW1, const float* __restrict__ cb1,
                         const float* __restrict__ oW1, const float* __restrict__ ob1,
                         const float* __restrict__ coW1, const float* __restrict__ cob1,
                         float* __restrict__ t1c, float* __restrict__ t1o, float* __restrict__ t1co)
{
  int z = blockIdx.x >> 8;
  int idx = ((blockIdx.x & 255) << 8) + threadIdx.x;
  int r = idx >> 7, c = idx & 127;
  if (z < 2) {
    const float* In = z ? xo_g : xc_g;
    const float* st = z ? stO : stC;
    const float* W = z ? oW1 : cW1;
    const float* bi = z ? ob1 : cb1;
    const float* mean = st + 256;
    const float* inv = st + 384;
    float acc = bi[c];
    for (int k = 0; k < 128; k++) {
      float a = (In[r * 128 + k] - mean[k]) * inv[k] + BNB;
      acc += a * W[k * 128 + c];
    }
    acc = fmaxf(acc, 0.f);
    (z ? t1o : t1c)[idx] = acc;
  } else {
    const float* mc = stC + 256; const float* vc = stC + 384;
    const float* mo = stO + 256; const float* vo = stO + 384;
    float acc = cob1[c];
    for (int k = 0; k < 128; k++) {
      float a = (xc_g[r * 128 + k] - mc[k]) * vc[k] + BNB;
      acc += a * coW1[k * 128 + c];
    }
    for (int k = 0; k < 128; k++) {
      float a = (xo_g[r * 128 + k] - mo[k]) * vo[k] + BNB;
      acc += a * coW1[(128 + k) * 128 + c];
    }
    acc = acc > 0.f ? acc : expm1f(acc);
    acc = acc > 0.f ? acc : expm1f(acc);
    t1co[idx] = acc;
  }
}

// batched 512-row stats (C=128), 16 blocks/set
__global__ void k_statsB(const float* __restrict__ i0, float* __restrict__ o0,
                         const float* __restrict__ i1, float* __restrict__ o1,
                         const float* __restrict__ i2, float* __restrict__ o2)
{
  int z = blockIdx.x >> 4;
  const float* X = z == 0 ? i0 : (z == 1 ? i1 : i2);
  float* st = z == 0 ? o0 : (z == 1 ? o1 : o2);
  int t = ((blockIdx.x & 15) << 8) + threadIdx.x;
  int c = t & 127, r0 = t >> 7;
  float s = 0.f, s2 = 0.f;
  for (int r = r0; r < 512; r += 32) {
    float v = X[r * 128 + c];
    s += v; s2 += v * v;
  }
  atomAdd(&st[c], s);
  atomAdd(&st[128 + c], s2);
}

// batched BN + logits + log_softmax: z = bid>>1
__global__ void k_lsmB(const float* __restrict__ t1c, const float* __restrict__ st1,
                       const float* __restrict__ cW2, const float* __restrict__ cb2,
                       const float* __restrict__ t1o, const float* __restrict__ st2,
                       const float* __restrict__ oW2, const float* __restrict__ ob2,
                       const float* __restrict__ t1co, const float* __restrict__ st3,
                       const float* __restrict__ coW2, const float* __restrict__ cob2,
                       float* __restrict__ out)
{
  int z = blockIdx.x >> 1;
  int r = ((blockIdx.x & 1) << 8) + threadIdx.x;
  const float* In = z == 0 ? t1c : (z == 1 ? t1o : t1co);
  const float* st = z == 0 ? st1 : (z == 1 ? st2 : st3);
  const float* W = z == 0 ? cW2 : (z == 1 ? oW2 : coW2);
  const float* bi = z == 0 ? cb2 : (z == 1 ? ob2 : cob2);
  float* o = out + z * 5120;
  const float* mean = st + 256;
  const float* inv = st + 384;
  float l[10];
  #pragma unroll
  for (int j = 0; j < 10; j++) l[j] = bi[j];
  for (int k = 0; k < 128; k++) {
    float a = (In[r * 128 + k] - mean[k]) * inv[k] + BNB;
    #pragma unroll
    for (int j = 0; j < 10; j++) l[j] += a * W[k * 10 + j];
  }
  float mx = l[0];
  #pragma unroll
  for (int j = 1; j < 10; j++) mx = fmaxf(mx, l[j]);
  float se = 0.f;
  #pragma unroll
  for (int j = 0; j < 10; j++) se += expf(l[j] - mx);
  float lse = mx + logf(se);
  #pragma unroll
  for (int j = 0; j < 10; j++) o[r * 10 + j] = l[j] - lse;
}

// =====================================================================
extern "C" void kernel_launch(void* const* d_in, const int* in_sizes, int n_in,
                              void* d_out, int out_size, void* d_ws, size_t ws_size,
                              hipStream_t stream)
{
  (void)n_in; (void)out_size; (void)ws_size;
  const float* x      = (const float*)d_in[0];
  const float* W_feat = (const float*)d_in[1];
  const float* convW  = (const float*)d_in[2];
  const float* convB  = (const float*)d_in[3];
  const float* eW     = (const float*)d_in[4];
  const float* eb     = (const float*)d_in[5];
  const float* naW    = (const float*)d_in[6];
  const float* nab    = (const float*)d_in[7];
  const float* xcW    = (const float*)d_in[8];
  const float* xcb    = (const float*)d_in[9];
  const float* xoW    = (const float*)d_in[10];
  const float* xob    = (const float*)d_in[11];
  const float* cW1    = (const float*)d_in[12];
  const float* cb1    = (const float*)d_in[13];
  const float* cW2    = (const float*)d_in[14];
  const float* cb2    = (const float*)d_in[15];
  const float* oW1    = (const float*)d_in[16];
  const float* ob1    = (const float*)d_in[17];
  const float* oW2    = (const float*)d_in[18];
  const float* ob2    = (const float*)d_in[19];
  const float* coW1   = (const float*)d_in[20];
  const float* cob1   = (const float*)d_in[21];
  const float* coW2   = (const float*)d_in[22];
  const float* cob2   = (const float*)d_in[23];
  const int* esrc  = (const int*)d_in[24];
  const int* edst  = (const int*)d_in[25];
  const int* batch = (const int*)d_in[26];
  const int E = in_sizes[24];
  const int N = in_sizes[26];
  float* out = (float*)d_out;

  char* wp = (char*)d_ws;
  auto alloc = [&](size_t bytes) -> char* {
    char* p = wp;
    wp += (bytes + 255) & ~size_t(255);
    return p;
  };

  // --- zero zone (single memset) ---
  char* zone = wp;
  float* degF   = (float*)alloc((size_t)N * 4);
  float* degC   = (float*)alloc((size_t)N * 4);
  float* degO   = (float*)alloc((size_t)N * 4);
  int*   cnt    = (int*)alloc((size_t)N * 4);
  int*   ctr    = (int*)alloc(16 * 4);
  float* statA  = (float*)alloc(1024 * 4);
  float* statB  = (float*)alloc(1024 * 4);
  float* stHC   = (float*)alloc(1024 * 4);
  float* stHO   = (float*)alloc(1024 * 4);
  float* st1    = (float*)alloc(1024 * 4);
  float* st2    = (float*)alloc(1024 * 4);
  float* st3    = (float*)alloc(1024 * 4);
  float* xc_g   = (float*)alloc(512 * 128 * 4);
  float* xo_g   = (float*)alloc(512 * 128 * 4);
  size_t zone_bytes = (size_t)(wp - zone);

  float*  A      = (float*)alloc((size_t)N * 128 * 4);
  unsigned short* Bbc = (unsigned short*)alloc((size_t)N * 128 * 2);
  unsigned short* Bbo = (unsigned short*)alloc((size_t)N * 128 * 2);
  float*  dis    = (float*)alloc((size_t)N * 4);
  float*  dis2   = (float*)alloc((size_t)N * 4);
  float*  disc   = (float*)alloc((size_t)N * 4);
  float*  diso   = (float*)alloc((size_t)N * 4);
  float*  selfcc = (float*)alloc((size_t)N * 4);
  float*  selfco = (float*)alloc((size_t)N * 4);
  float*  na0    = (float*)alloc((size_t)N * 4);
  float4* PQ     = (float4*)alloc((size_t)N * 16);
  float2* hn     = (float2*)alloc((size_t)N * 8);
  float2* nlog   = (float2*)alloc((size_t)N * 8);
  int*    rs     = (int*)alloc((size_t)(N + 1) * 4);
  int2*   icP    = (int2*)alloc((size_t)(E + N) * 8);
  int2*   icC    = (int2*)alloc((size_t)(E + N) * 8);
  int2*   icO    = (int2*)alloc((size_t)(E + N) * 8);
  float*  attE   = (float*)alloc((size_t)E * 4);
  int*    edgepos= (int*)alloc((size_t)E * 4);
  int*    wst    = (int*)alloc((size_t)8200 * 4);
  unsigned short* WtAll = (unsigned short*)alloc((size_t)6 * 16384 * 2);
  float*  t1c    = (float*)alloc(512 * 128 * 4);
  float*  t1o    = (float*)alloc(512 * 128 * 4);
  float*  t1co   = (float*)alloc(512 * 128 * 4);

  const int TPB = 256;
  const int NW = 8192;  // gather work chunks
  int gE  = (E + TPB - 1) / TPB;
  int gEN = (E + N + TPB - 1) / TPB;
  int gN  = (N + TPB - 1) / TPB;
  int gMM = (N + 63) / 64;
  int S   = E + N;

  hipMemsetAsync(zone, 0, zone_bytes, stream);

  // ---- graph structure ----
  k_hist<<<gE, TPB, 0, stream>>>(esrc, edst, E, degF, cnt);
  k_rsqrt1<<<gN, TPB, 0, stream>>>(degF, dis, dis2, N);
  k_scan<<<1, 1024, 0, stream>>>(cnt, N, rs);
  k_fillB<<<gEN, TPB, 0, stream>>>(esrc, edst, E, N, rs, cnt, dis, dis2, icP, edgepos);
  k_wstart<<<(NW + 1 + TPB - 1) / TPB, TPB, 0, stream>>>(rs, N, S, NW, wst);
  k_prepW6<<<384, TPB, 0, stream>>>(W_feat, convW, xcW, xoW, WtAll);

  // ---- h = relu(BN(x) @ W_feat), stats(h) -> statB ----
  k_stats<<<784, TPB, 0, stream>>>(x, N, statA);
  k_finN<<<1, 256, 0, stream>>>(statA, N, statA, N, statA, N);
  k_mm_mfma<1, 0, 1><<<gMM, TPB, 0, stream>>>(x, statA, WtAll, A, N, 0, nullptr, statB);
  k_finN<<<1, 256, 0, stream>>>(statB, N, statB, N, statB, N);

  // ---- 3 GCN layers ----
  for (int l = 0; l < 3; l++) {
    k_mm_mfma<0, 1, 0><<<gMM, TPB, 0, stream>>>(A, statB, WtAll + (size_t)(1 + l) * 16384, Bbc, N, 0, nullptr, nullptr);
    if (l < 2) {
      k_gath<0><<<2048, TPB, 0, stream>>>(Bbc, icP, convB + l * 128, A,
                                          nullptr, nullptr, nullptr, nullptr, nullptr,
                                          rs, wst, NW, nullptr, ctr + l, statB);
      k_finN<<<1, 256, 0, stream>>>(statB, N, statB, N, statB, N);
    } else {
      k_gath<1><<<2048, TPB, 0, stream>>>(Bbc, icP, convB + l * 128, A,
                                          nullptr, nullptr, nullptr, nullptr, nullptr,
                                          rs, wst, NW, nullptr, ctr + l, nullptr);
    }
  }

  // ---- attention ----
  k_pqhn<<<1024, TPB, 0, stream>>>(A, eW, naW, PQ, hn, N);
  k_natt<<<gN, TPB, 0, stream>>>(hn, rs, icP, nab, nlog, N);
  k_edge<<<gE, TPB, 0, stream>>>(esrc, edst, E, PQ, eb, attE, degC, degO);
  k_nodefin<<<gN, TPB, 0, stream>>>(degC, degO, nlog, disc, diso, selfcc, selfco, na0, N);
  k_edge2B<<<gEN, TPB, 0, stream>>>(esrc, edst, E, N, attE, edgepos, rs, disc, diso, selfcc, selfco, icC, icO);

  // ---- xc / xo BN stats ----
  k_stats2<<<784, TPB, 0, stream>>>(A, N, statA, statB, na0);
  k_finN<<<2, 256, 0, stream>>>(statA, N, statB, N, statB, N);

  // ---- xc / xo matmuls + fused weighted gather+pool ----
  k_mm_mfma<0, 1, 0><<<gMM, TPB, 0, stream>>>(A, statA, WtAll + (size_t)4 * 16384, Bbc, N, 1, na0, nullptr);
  k_mm_mfma<0, 1, 0><<<gMM, TPB, 0, stream>>>(A, statB, WtAll + (size_t)5 * 16384, Bbo, N, 2, na0, nullptr);
  k_gath<2><<<4096, TPB, 0, stream>>>(Bbc, icC, xcb, nullptr,
                                      Bbo, icO, xob, xo_g, xc_g,
                                      rs, wst, NW, batch, ctr + 4, nullptr);

  // ---- heads ----
  k_statsB<<<32, TPB, 0, stream>>>(xc_g, stHC, xo_g, stHO, xo_g, stHO);
  k_finN<<<2, 256, 0, stream>>>(stHC, 512, stHO, 512, stHO, 512);
  k_heads1<<<768, TPB, 0, stream>>>(xc_g, xo_g, stHC, stHO,
                                    cW1, cb1, oW1, ob1, coW1, cob1,
                                    t1c, t1o, t1co);
  k_statsB<<<48, TPB, 0, stream>>>(t1c, st1, t1o, st2, t1co, st3);
  k_finN<<<3, 256, 0, stream>>>(st1, 512, st2, 512, st3, 512);
  k_lsmB<<<6, TPB, 0, stream>>>(t1c, st1, cW2, cb2,
                                t1o, st2, oW2, ob2,
                                t1co, st3, coW2, cob2, out);
}

// Round 5
// 874.408 us; speedup vs baseline: 1.8754x; 1.8754x over previous
//
#include <hip/hip_runtime.h>
#include <math.h>

#define EPS 1e-5f
#define BNB 1e-4f

typedef __attribute__((ext_vector_type(8))) short short8;
typedef __attribute__((ext_vector_type(4))) float f32x4;
typedef __attribute__((ext_vector_type(4))) unsigned short ushort4_t;

static __device__ __forceinline__ void atomAdd(float* p, float v) { unsafeAtomicAdd(p, v); }

static __device__ __forceinline__ unsigned short f2bf(float f) {
  unsigned u = __float_as_uint(f);
  unsigned r = (u + 0x7fffu + ((u >> 16) & 1u)) >> 16;
  return (unsigned short)r;
}
static __device__ __forceinline__ float bflo(unsigned u) { return __uint_as_float(u << 16); }
static __device__ __forceinline__ float bfhi(unsigned u) { return __uint_as_float(u & 0xffff0000u); }

// ---------------- column stats, row-major input (x only) ----------------
__global__ void k_stats(const float* __restrict__ X, int R, float* __restrict__ st)
{
  const int C = 128;
  int T = gridDim.x * blockDim.x;
  int t = blockIdx.x * blockDim.x + threadIdx.x;
  int c = t % C, r0 = t / C, rsr = T / C;
  float s = 0.f, s2 = 0.f;
  for (int r = r0; r < R; r += rsr) {
    float v = X[(size_t)r * C + c];
    s += v; s2 += v * v;
  }
  atomAdd(&st[c], s);
  atomAdd(&st[C + c], s2);
}

// ---------------- column stats, PLANE layout input ----------------
__global__ void k_statsP(const float* __restrict__ A, int R, float* __restrict__ st)
{
  const int C = 128;
  int T = gridDim.x * blockDim.x;
  int t = blockIdx.x * blockDim.x + threadIdx.x;
  int c = t % C, r0 = t / C, rsr = T / C;
  const float* base = A + (size_t)(c >> 5) * R * 32 + (c & 31);
  float s = 0.f, s2 = 0.f;
  for (int r = r0; r < R; r += rsr) {
    float v = base[(size_t)r * 32];
    s += v; s2 += v * v;
  }
  atomAdd(&st[c], s);
  atomAdd(&st[C + c], s2);
}

// fused stats for xc = na*h and xo = (1-na)*h, PLANE layout
__global__ void k_stats2P(const float* __restrict__ A, int R,
                          float* __restrict__ stA, float* __restrict__ stB,
                          const float* __restrict__ na)
{
  const int C = 128;
  int T = gridDim.x * blockDim.x;
  int t = blockIdx.x * blockDim.x + threadIdx.x;
  int c = t % C, r0 = t / C, rsr = T / C;
  const float* base = A + (size_t)(c >> 5) * R * 32 + (c & 31);
  float sa = 0, sa2 = 0, sb = 0, sb2 = 0;
  for (int r = r0; r < R; r += rsr) {
    float v = base[(size_t)r * 32];
    float a = na[r] * v;
    float b = (1.f - na[r]) * v;
    sa += a; sa2 += a * a; sb += b; sb2 += b * b;
  }
  atomAdd(&stA[c], sa); atomAdd(&stA[C + c], sa2);
  atomAdd(&stB[c], sb); atomAdd(&stB[C + c], sb2);
}

// st layout: [0,C) sum, [C,2C) sumsq, [2C,3C) mean, [3C,4C) inv; rezeroes sums.
__global__ void k_finN(float* s0, int R0, float* s1, int R1, float* s2, int R2)
{
  int z = blockIdx.x;
  float* st = z == 0 ? s0 : (z == 1 ? s1 : s2);
  int R = z == 0 ? R0 : (z == 1 ? R1 : R2);
  const int C = 128;
  int c = threadIdx.x;
  if (c < C) {
    float m = st[c] / R;
    float v = st[C + c] / R - m * m;
    st[2 * C + c] = m;
    st[3 * C + c] = rsqrtf(v + EPS);
    st[c] = 0.f; st[C + c] = 0.f;
  }
}

// ---------------- weight prep: 6 matrices -> bf16 transposed+swizzled ----------------
__global__ void k_prepW6(const float* __restrict__ W_feat, const float* __restrict__ convW,
                         const float* __restrict__ xcW, const float* __restrict__ xoW,
                         unsigned short* __restrict__ Wt)
{
  int idx = blockIdx.x * 256 + threadIdx.x;  // 6*16384
  int which = idx >> 14, e = idx & 16383;
  const float* W = which == 0 ? W_feat
                 : (which <= 3 ? convW + (size_t)(which - 1) * 16384
                 : (which == 4 ? xcW : xoW));
  int n = e >> 7, k = e & 127;
  Wt[((size_t)which << 14) + (n << 7) + (((k >> 3) ^ (n & 7)) << 3) + (k & 7)] = f2bf(W[k * 128 + n]);
}

// ---------------- MFMA matmul: Out(planes) = act( BN(scale*A) @ W ) ----------------
// PLANEIN: A in plane layout (else row-major). Output ALWAYS plane layout.
template<int ACT, int OUTBF16, int STATS, int PLANEIN>
__global__ __launch_bounds__(256) void k_mm_mfma(
    const float* __restrict__ A, const float* __restrict__ st,
    const unsigned short* __restrict__ Wt, void* __restrict__ OutV,
    int Nrows, int scale_mode, const float* __restrict__ na,
    float* __restrict__ stOut)
{
  __shared__ unsigned short sA[64 * 128];
  __shared__ unsigned short sW[128 * 128];
  int t = threadIdx.x;
  int r0 = blockIdx.x * 64;
  size_t N32 = (size_t)Nrows * 32;
  {
    const short8* src = (const short8*)Wt;
    short8* dst = (short8*)sW;
    #pragma unroll
    for (int j = 0; j < 8; j++) dst[t + 256 * j] = src[t + 256 * j];
  }
  {
    int r = t >> 2;
    int rg = r0 + r;
    bool valid = rg < Nrows;
    float sc = 1.f;
    if (scale_mode == 1) sc = valid ? na[rg] : 0.f;
    else if (scale_mode == 2) sc = valid ? (1.f - na[rg]) : 0.f;
    #pragma unroll
    for (int i = 0; i < 8; i++) {
      int k = ((t & 3) << 2) + (i << 4);
      float4 va = make_float4(0.f, 0.f, 0.f, 0.f);
      if (valid) {
        if (PLANEIN) va = *(const float4*)(A + (size_t)(k >> 5) * N32 + (size_t)rg * 32 + (k & 31));
        else         va = *(const float4*)(A + (size_t)rg * 128 + k);
      }
      float4 mm = *(const float4*)(st + 256 + k);
      float4 iv = *(const float4*)(st + 384 + k);
      ushort4_t w;
      w.x = f2bf((sc * va.x - mm.x) * iv.x + BNB);
      w.y = f2bf((sc * va.y - mm.y) * iv.y + BNB);
      w.z = f2bf((sc * va.z - mm.z) * iv.z + BNB);
      w.w = f2bf((sc * va.w - mm.w) * iv.w + BNB);
      *(ushort4_t*)(&sA[(r << 7) + (((k >> 3) ^ (r & 7)) << 3) + (k & 7)]) = w;
    }
  }
  __syncthreads();

  int w = t >> 6, l = t & 63;
  int n0 = w * 32;
  int la = l & 15, hi = l >> 4;
  f32x4 acc[4][2];
  #pragma unroll
  for (int m = 0; m < 4; m++)
    #pragma unroll
    for (int nf = 0; nf < 2; nf++) {
      acc[m][nf][0] = 0.f; acc[m][nf][1] = 0.f;
      acc[m][nf][2] = 0.f; acc[m][nf][3] = 0.f;
    }
  #pragma unroll
  for (int ks = 0; ks < 4; ks++) {
    int slot = ks * 4 + hi;
    short8 af[4], bfr[2];
    #pragma unroll
    for (int m = 0; m < 4; m++) {
      int r = 16 * m + la;
      af[m] = *(const short8*)(&sA[(r << 7) + ((slot ^ (r & 7)) << 3)]);
    }
    #pragma unroll
    for (int nf = 0; nf < 2; nf++) {
      int n = n0 + 16 * nf + la;
      bfr[nf] = *(const short8*)(&sW[(n << 7) + ((slot ^ (n & 7)) << 3)]);
    }
    #pragma unroll
    for (int m = 0; m < 4; m++)
      #pragma unroll
      for (int nf = 0; nf < 2; nf++)
        acc[m][nf] = __builtin_amdgcn_mfma_f32_16x16x32_bf16(af[m], bfr[nf], acc[m][nf], 0, 0, 0);
  }
  #pragma unroll
  for (int nf = 0; nf < 2; nf++) {
    int c = n0 + 16 * nf + la;
    size_t pbase = (size_t)(c >> 5) * N32 + (c & 31);
    float scol = 0.f, qcol = 0.f;
    #pragma unroll
    for (int m = 0; m < 4; m++) {
      #pragma unroll
      for (int q = 0; q < 4; q++) {
        int r = r0 + 16 * m + hi * 4 + q;
        float v = acc[m][nf][q];
        if (ACT == 1) v = fmaxf(v, 0.f);
        if (r < Nrows) {
          if (OUTBF16) ((unsigned short*)OutV)[pbase + (size_t)r * 32] = f2bf(v);
          else         ((float*)OutV)[pbase + (size_t)r * 32] = v;
          if (STATS) { scol += v; qcol += v * v; }
        }
      }
    }
    if (STATS) {
      scol += __shfl_xor(scol, 16); scol += __shfl_xor(scol, 32);
      qcol += __shfl_xor(qcol, 16); qcol += __shfl_xor(qcol, 32);
      if (hi == 0) { atomAdd(&stOut[c], scol); atomAdd(&stOut[128 + c], qcol); }
    }
  }
}

// ---------------- graph structure ----------------
__global__ void k_hist(const int* __restrict__ src, const int* __restrict__ dst, int E,
                       float* __restrict__ degF, int* __restrict__ cnt)
{
  int e = blockIdx.x * blockDim.x + threadIdx.x;
  if (e < E) {
    atomAdd(&degF[src[e]], 1.f);
    atomicAdd(&cnt[dst[e]], 1);
  }
}
__global__ void k_rsqrt1(const float* __restrict__ deg, float* __restrict__ dis,
                         float* __restrict__ dis2, int Nn)
{
  int i = blockIdx.x * blockDim.x + threadIdx.x;
  if (i < Nn) {
    float d = rsqrtf(deg[i] + 1.f);
    dis[i] = d;
    dis2[i] = d * d;
  }
}
// exclusive scan over padded lengths ((cnt+1) rounded up to mult of 4); zeroes cnt
__global__ void k_scan(int* __restrict__ cnt, int Nn, int* __restrict__ rs4)
{
  __shared__ int sd[1024];
  __shared__ int srun;
  int t = threadIdx.x;
  if (t == 0) srun = 0;
  __syncthreads();
  for (int base = 0; base < Nn; base += 1024) {
    int v = 0;
    if (base + t < Nn) { v = (cnt[base + t] + 4) & ~3; cnt[base + t] = 0; }
    sd[t] = v;
    __syncthreads();
    for (int off = 1; off < 1024; off <<= 1) {
      int x = (t >= off) ? sd[t - off] : 0;
      __syncthreads();
      sd[t] += x;
      __syncthreads();
    }
    int incl = sd[t];
    int run = srun;
    if (base + t < Nn) rs4[base + t] = run + incl - v;
    __syncthreads();
    if (t == 1023) srun = run + incl;
    __syncthreads();
  }
  if (t == 0) rs4[Nn] = srun;
}
// fill CSR: data edges at slot 1+, self at slot 0 (pads stay zero from memset)
__global__ void k_fillB(const int* __restrict__ src, const int* __restrict__ dst, int E, int Nn,
                        const int* __restrict__ rs4, int* __restrict__ cnt,
                        const float* __restrict__ dis, const float* __restrict__ dis2,
                        int2* __restrict__ icP, int* __restrict__ edgepos)
{
  int e = blockIdx.x * blockDim.x + threadIdx.x;
  if (e < E) {
    int d = dst[e], s = src[e];
    int k = atomicAdd(&cnt[d], 1);
    int pos = rs4[d] + 1 + k;
    icP[pos] = make_int2(s, __float_as_int(dis[s] * dis[d]));
    edgepos[e] = pos;
  } else if (e < E + Nn) {
    int i = e - E;
    icP[rs4[i]] = make_int2(i, __float_as_int(dis2[i]));
  }
}
// slot-balanced wave ranges over padded CSR
__global__ void k_wstart(const int* __restrict__ rs4, int Nn, int nw, int* __restrict__ wst)
{
  int w = blockIdx.x * blockDim.x + threadIdx.x;
  if (w > nw) return;
  int S4 = rs4[Nn];
  long long spw = (S4 + nw - 1) / nw;
  long long target = (long long)w * spw;
  int lo = 0, hi = Nn;
  while (lo < hi) {
    int mid = (lo + hi) >> 1;
    if ((long long)rs4[mid] < target) lo = mid + 1; else hi = mid;
  }
  wst[w] = lo;
}

// ---------------- plane-partitioned gather ----------------
// MODE 1: relu + write A planes. MODE 2: elu + pool (dual branch xc/xo).
// Pass p handles columns [32p,32p+32). XCD affinity: combo = blockIdx&7.
//   MODE1 grid 2048: p = combo>>1, wave-half = combo&1.
//   MODE2 grid 4096: branch = combo&1, p = combo>>1.
template<int MODE>
__global__ __launch_bounds__(256) void k_gplane(
    const unsigned short* __restrict__ Hb0, const int2* __restrict__ ic0,
    const float* __restrict__ bias0, float* __restrict__ OutP,
    const unsigned short* __restrict__ Hb1, const int2* __restrict__ ic1,
    const float* __restrict__ bias1,
    float* __restrict__ outg0, float* __restrict__ outg1,
    const int* __restrict__ rs4, const int* __restrict__ wst,
    const int* __restrict__ batch, int Nn)
{
  int t = threadIdx.x, lane = t & 63, wslot = t >> 6;
  int li = lane & 15, s4 = lane >> 4;
  int bid = blockIdx.x;
  int combo = bid & 7;
  int j = bid >> 3;
  int p, wp;
  const unsigned short* Hb; const int2* ic; const float* bias; float* outg;
  if (MODE == 2) {
    int branch = combo & 1; p = combo >> 1;
    Hb = branch ? Hb1 : Hb0; ic = branch ? ic1 : ic0;
    bias = branch ? bias1 : bias0; outg = branch ? outg1 : outg0;
    wp = j * 4 + wslot;
  } else {
    p = combo >> 1;
    Hb = Hb0; ic = ic0; bias = bias0; outg = nullptr;
    wp = (combo & 1) * 1024 + j * 4 + wslot;
  }
  size_t N32 = (size_t)Nn * 32;
  const unsigned short* Hp = Hb + (size_t)p * N32;
  float* Ap = OutP ? (OutP + (size_t)p * N32) : nullptr;
  int c0 = p * 32 + li * 2;
  float bx = bias[c0], by = bias[c0 + 1];
  int nodeLo = wst[wp], nodeHi = wst[wp + 1];

  int wbase = 0, wend = 0, wix = 0, wcf = 0;
  int curg = -1; float gx = 0.f, gy = 0.f;
  int ci = nodeLo;

  while (ci < nodeHi) {
    int nb = min(nodeHi - ci, 63);
    int rsl = (lane <= nb) ? rs4[ci + lane] : 0;
    int btl = 0;
    if (MODE == 2) btl = (lane < nb) ? batch[ci + lane] : 0;
    int gEnd = __shfl(rsl, nb);
    int n = 0;
    int je = __shfl(rsl, 1);
    float ax = 0.f, ay = 0.f;
    int g = __shfl(rsl, 0);
    unsigned uA, uB; float cfA, cfB;

    auto ISSUE = [&](int gg, unsigned& u, float& cf) {
      if (gg >= wend) {
        wbase = gg; wend = gg + 64;
        int2 v = ic[(size_t)gg + lane];
        wix = v.x; wcf = v.y;
      }
      int slot = gg - wbase + s4;
      int sidx = __shfl(wix, slot);
      cf = __int_as_float(__shfl(wcf, slot));
      u = *(const unsigned*)(Hp + (size_t)sidx * 32 + (li << 1));
    };
    auto FLUSH = [&](int nn) {
      float rx = ax; rx += __shfl_xor(rx, 16); rx += __shfl_xor(rx, 32);
      float ry = ay; ry += __shfl_xor(ry, 16); ry += __shfl_xor(ry, 32);
      rx += bx; ry += by;
      if (MODE == 1) {
        rx = fmaxf(rx, 0.f); ry = fmaxf(ry, 0.f);
        if (lane < 16)
          *(float2*)(Ap + (size_t)(ci + nn) * 32 + (li << 1)) = make_float2(rx, ry);
      } else {
        rx = rx > 0.f ? rx : expm1f(rx);
        ry = ry > 0.f ? ry : expm1f(ry);
        int bt = __shfl(btl, nn);
        if (bt != curg) {
          if (curg >= 0 && lane < 16) {
            atomAdd(&outg[curg * 128 + c0], gx);
            atomAdd(&outg[curg * 128 + c0 + 1], gy);
          }
          curg = bt; gx = rx; gy = ry;
        } else { gx += rx; gy += ry; }
      }
    };
    auto CONSUME = [&](int gg, unsigned u, float cf) {
      if (gg >= je) {
        FLUSH(n);
        n++; je = __shfl(rsl, n + 1);
        ax = 0.f; ay = 0.f;
      }
      ax = fmaf(cf, bflo(u), ax);
      ay = fmaf(cf, bfhi(u), ay);
    };

    ISSUE(g, uA, cfA);
    for (;;) {
      int g1 = g + 4;
      if (g1 >= gEnd) { CONSUME(g, uA, cfA); break; }
      ISSUE(g1, uB, cfB);
      CONSUME(g, uA, cfA);
      int g2 = g1 + 4;
      if (g2 >= gEnd) { CONSUME(g1, uB, cfB); break; }
      ISSUE(g2, uA, cfA);
      CONSUME(g1, uB, cfB);
      g = g2;
    }
    FLUSH(n);
    ci += nb;
  }
  if (MODE == 2 && curg >= 0 && lane < 16) {
    atomAdd(&outg[curg * 128 + c0], gx);
    atomAdd(&outg[curg * 128 + c0 + 1], gy);
  }
}

// ---------------- per-node projections P,Q + hn (PLANE input) ----------------
__global__ __launch_bounds__(256) void k_pqhnP(
    const float* __restrict__ H, const float* __restrict__ eW,
    const float* __restrict__ naW, float4* __restrict__ PQ,
    float2* __restrict__ hn, int Nn)
{
  __shared__ float w[128][6];
  int t = threadIdx.x;
  if (t < 128) {
    w[t][0] = eW[2 * t];       w[t][1] = eW[2 * t + 1];
    w[t][2] = eW[256 + 2 * t]; w[t][3] = eW[256 + 2 * t + 1];
    w[t][4] = naW[2 * t];      w[t][5] = naW[2 * t + 1];
  }
  __syncthreads();
  int lane = t & 63;
  int wid = (blockIdx.x * 256 + t) >> 6;
  int nwv = (gridDim.x * 256) >> 6;
  size_t N32 = (size_t)Nn * 32;
  const float* base = H + (size_t)(lane >> 4) * N32 + ((2 * lane) & 31);
  for (int i = wid; i < Nn; i += nwv) {
    const float2 h2 = *(const float2*)(base + (size_t)i * 32);
    int k0 = lane * 2, k1 = lane * 2 + 1;
    float p0 = h2.x * w[k0][0] + h2.y * w[k1][0];
    float p1 = h2.x * w[k0][1] + h2.y * w[k1][1];
    float q0 = h2.x * w[k0][2] + h2.y * w[k1][2];
    float q1 = h2.x * w[k0][3] + h2.y * w[k1][3];
    float n0 = h2.x * w[k0][4] + h2.y * w[k1][4];
    float n1 = h2.x * w[k0][5] + h2.y * w[k1][5];
    #pragma unroll
    for (int o = 32; o > 0; o >>= 1) {
      p0 += __shfl_xor(p0, o); p1 += __shfl_xor(p1, o);
      q0 += __shfl_xor(q0, o); q1 += __shfl_xor(q1, o);
      n0 += __shfl_xor(n0, o); n1 += __shfl_xor(n1, o);
    }
    if (lane == 0) {
      PQ[i] = make_float4(p0, p1, q0, q1);
      hn[i] = make_float2(n0, n1);
    }
  }
}

// node-att propagate (2 channels; self edge in CSR, pads are zero)
__global__ void k_natt(const float2* __restrict__ hn,
                       const int* __restrict__ rs4, const int2* __restrict__ icP,
                       const float* __restrict__ nab, float2* __restrict__ nlog, int Nn)
{
  int i = blockIdx.x * blockDim.x + threadIdx.x;
  if (i >= Nn) return;
  float a0 = nab[0], a1 = nab[1];
  int jb = rs4[i], je = rs4[i + 1];
  for (int j = jb; j < je; j++) {
    int2 v = icP[j];
    float c = __int_as_float(v.y);
    float2 hs = hn[v.x];
    a0 += c * hs.x;
    a1 += c * hs.y;
  }
  nlog[i] = make_float2(a0, a1);
}

// per-edge attention + weighted-degree accumulation
__global__ void k_edge(const int* __restrict__ src, const int* __restrict__ dst, int E,
                       const float4* __restrict__ PQ, const float* __restrict__ eb,
                       float* __restrict__ attE,
                       float* __restrict__ degc, float* __restrict__ dego)
{
  int e = blockIdx.x * blockDim.x + threadIdx.x;
  if (e >= E) return;
  int s = src[e], d = dst[e];
  float4 ps = PQ[s];
  float4 pd = PQ[d];
  float ld = (ps.x - ps.y) + (pd.z - pd.w) + (eb[0] - eb[1]);
  float att = 1.f / (1.f + expf(-ld));
  attE[e] = att;
  atomAdd(&degc[s], att);
  atomAdd(&dego[s], 1.f - att);
}

__global__ void k_nodefin(const float* __restrict__ degc, const float* __restrict__ dego,
                          const float2* __restrict__ nlog,
                          float* __restrict__ disc, float* __restrict__ diso,
                          float* __restrict__ selfcc, float* __restrict__ selfco,
                          float* __restrict__ na0, int Nn)
{
  int i = blockIdx.x * blockDim.x + threadIdx.x;
  if (i >= Nn) return;
  float dc = rsqrtf(degc[i] + 1.f);
  float dd = rsqrtf(dego[i] + 1.f);
  disc[i] = dc; diso[i] = dd;
  selfcc[i] = dc * dc; selfco[i] = dd * dd;
  float2 l = nlog[i];
  na0[i] = 1.f / (1.f + expf(-(l.x - l.y)));
}

// weighted (idx,coef) pairs into CSR order (edges + self; pads stay zero)
__global__ void k_edge2B(const int* __restrict__ src, const int* __restrict__ dst, int E, int Nn,
                         const float* __restrict__ attE, const int* __restrict__ edgepos,
                         const int* __restrict__ rs4,
                         const float* __restrict__ disc, const float* __restrict__ diso,
                         const float* __restrict__ selfcc, const float* __restrict__ selfco,
                         int2* __restrict__ icC, int2* __restrict__ icO)
{
  int e = blockIdx.x * blockDim.x + threadIdx.x;
  if (e < E) {
    int s = src[e], d = dst[e];
    int pos = edgepos[e];
    float att = attE[e];
    icC[pos] = make_int2(s, __float_as_int(disc[s] * att * disc[d]));
    icO[pos] = make_int2(s, __float_as_int(diso[s] * (1.f - att) * diso[d]));
  } else if (e < E + Nn) {
    int i = e - E;
    int pp = rs4[i];
    icC[pp] = make_int2(i, __float_as_int(selfcc[i]));
    icO[pp] = make_int2(i, __float_as_int(selfco[i]));
  }
}

// ---------------- heads ----------------
__global__ void k_heads1(const float* __restrict__ xc_g, const float* __restrict__ xo_g,
                         const float* __restrict__ stC, const float* __restrict__ stO,
                         const float* __restrict__ cW1, const float* __restrict__ cb1,
                         const float* __restrict__ oW1, const float* __restrict__ ob1,
                         const float* __restrict__ coW1, const float* __restrict__ cob1,
                         float* __restrict__ t1c, float* __restrict__ t1o, float* __restrict__ t1co)
{
  int z = blockIdx.x >> 8;
  int idx = ((blockIdx.x & 255) << 8) + threadIdx.x;
  int r = idx >> 7, c = idx & 127;
  if (z < 2) {
    const float* In = z ? xo_g : xc_g;
    const float* st = z ? stO : stC;
    const float* W = z ? oW1 : cW1;
    const float* bi = z ? ob1 : cb1;
    const float* mean = st + 256;
    const float* inv = st + 384;
    float acc = bi[c];
    for (int k = 0; k < 128; k++) {
      float a = (In[r * 128 + k] - mean[k]) * inv[k] + BNB;
      acc += a * W[k * 128 + c];
    }
    acc = fmaxf(acc, 0.f);
    (z ? t1o : t1c)[idx] = acc;
  } else {
    const float* mc = stC + 256; const float* vc = stC + 384;
    const float* mo = stO + 256; const float* vo = stO + 384;
    float acc = cob1[c];
    for (int k = 0; k < 128; k++) {
      float a = (xc_g[r * 128 + k] - mc[k]) * vc[k] + BNB;
      acc += a * coW1[k * 128 + c];
    }
    for (int k = 0; k < 128; k++) {
      float a = (xo_g[r * 128 + k] - mo[k]) * vo[k] + BNB;
      acc += a * coW1[(128 + k) * 128 + c];
    }
    acc = acc > 0.f ? acc : expm1f(acc);
    acc = acc > 0.f ? acc : expm1f(acc);
    t1co[idx] = acc;
  }
}

__global__ void k_statsB(const float* __restrict__ i0, float* __restrict__ o0,
                         const float* __restrict__ i1, float* __restrict__ o1,
                         const float* __restrict__ i2, float* __restrict__ o2)
{
  int z = blockIdx.x >> 4;
  const float* X = z == 0 ? i0 : (z == 1 ? i1 : i2);
  float* st = z == 0 ? o0 : (z == 1 ? o1 : o2);
  int t = ((blockIdx.x & 15) << 8) + threadIdx.x;
  int c = t & 127, r0 = t >> 7;
  float s = 0.f, s2 = 0.f;
  for (int r = r0; r < 512; r += 32) {
    float v = X[r * 128 + c];
    s += v; s2 += v * v;
  }
  atomAdd(&st[c], s);
  atomAdd(&st[128 + c], s2);
}

__global__ void k_lsmB(const float* __restrict__ t1c, const float* __restrict__ st1,
                       const float* __restrict__ cW2, const float* __restrict__ cb2,
                       const float* __restrict__ t1o, const float* __restrict__ st2,
                       const float* __restrict__ oW2, const float* __restrict__ ob2,
                       const float* __restrict__ t1co, const float* __restrict__ st3,
                       const float* __restrict__ coW2, const float* __restrict__ cob2,
                       float* __restrict__ out)
{
  int z = blockIdx.x >> 1;
  int r = ((blockIdx.x & 1) << 8) + threadIdx.x;
  const float* In = z == 0 ? t1c : (z == 1 ? t1o : t1co);
  const float* st = z == 0 ? st1 : (z == 1 ? st2 : st3);
  const float* W = z == 0 ? cW2 : (z == 1 ? oW2 : coW2);
  const float* bi = z == 0 ? cb2 : (z == 1 ? ob2 : cob2);
  float* o = out + z * 5120;
  const float* mean = st + 256;
  const float* inv = st + 384;
  float l[10];
  #pragma unroll
  for (int j = 0; j < 10; j++) l[j] = bi[j];
  for (int k = 0; k < 128; k++) {
    float a = (In[r * 128 + k] - mean[k]) * inv[k] + BNB;
    #pragma unroll
    for (int j = 0; j < 10; j++) l[j] += a * W[k * 10 + j];
  }
  float mx = l[0];
  #pragma unroll
  for (int j = 1; j < 10; j++) mx = fmaxf(mx, l[j]);
  float se = 0.f;
  #pragma unroll
  for (int j = 0; j < 10; j++) se += expf(l[j] - mx);
  float lse = mx + logf(se);
  #pragma unroll
  for (int j = 0; j < 10; j++) o[r * 10 + j] = l[j] - lse;
}

// =====================================================================
extern "C" void kernel_launch(void* const* d_in, const int* in_sizes, int n_in,
                              void* d_out, int out_size, void* d_ws, size_t ws_size,
                              hipStream_t stream)
{
  (void)n_in; (void)out_size; (void)ws_size;
  const float* x      = (const float*)d_in[0];
  const float* W_feat = (const float*)d_in[1];
  const float* convW  = (const float*)d_in[2];
  const float* convB  = (const float*)d_in[3];
  const float* eW     = (const float*)d_in[4];
  const float* eb     = (const float*)d_in[5];
  const float* naW    = (const float*)d_in[6];
  const float* nab    = (const float*)d_in[7];
  const float* xcW    = (const float*)d_in[8];
  const float* xcb    = (const float*)d_in[9];
  const float* xoW    = (const float*)d_in[10];
  const float* xob    = (const float*)d_in[11];
  const float* cW1    = (const float*)d_in[12];
  const float* cb1    = (const float*)d_in[13];
  const float* cW2    = (const float*)d_in[14];
  const float* cb2    = (const float*)d_in[15];
  const float* oW1    = (const float*)d_in[16];
  const float* ob1    = (const float*)d_in[17];
  const float* oW2    = (const float*)d_in[18];
  const float* ob2    = (const float*)d_in[19];
  const float* coW1   = (const float*)d_in[20];
  const float* cob1   = (const float*)d_in[21];
  const float* coW2   = (const float*)d_in[22];
  const float* cob2   = (const float*)d_in[23];
  const int* esrc  = (const int*)d_in[24];
  const int* edst  = (const int*)d_in[25];
  const int* batch = (const int*)d_in[26];
  const int E = in_sizes[24];
  const int N = in_sizes[26];
  float* out = (float*)d_out;

  char* wp = (char*)d_ws;
  auto alloc = [&](size_t bytes) -> char* {
    char* p = wp;
    wp += (bytes + 255) & ~size_t(255);
    return p;
  };

  const size_t ICSZ = (size_t)E + 4 * (size_t)N + 64;

  // --- zero zone (single memset): counters, stats, pools, padded CSR arrays ---
  char* zone = wp;
  float* degF   = (float*)alloc((size_t)N * 4);
  float* degC   = (float*)alloc((size_t)N * 4);
  float* degO   = (float*)alloc((size_t)N * 4);
  int*   cnt    = (int*)alloc((size_t)N * 4);
  float* statA  = (float*)alloc(1024 * 4);
  float* statB  = (float*)alloc(1024 * 4);
  float* stHC   = (float*)alloc(1024 * 4);
  float* stHO   = (float*)alloc(1024 * 4);
  float* st1    = (float*)alloc(1024 * 4);
  float* st2    = (float*)alloc(1024 * 4);
  float* st3    = (float*)alloc(1024 * 4);
  float* xc_g   = (float*)alloc(512 * 128 * 4);
  float* xo_g   = (float*)alloc(512 * 128 * 4);
  int2*  icP    = (int2*)alloc(ICSZ * 8);
  int2*  icC    = (int2*)alloc(ICSZ * 8);
  int2*  icO    = (int2*)alloc(ICSZ * 8);
  size_t zone_bytes = (size_t)(wp - zone);

  float*  A      = (float*)alloc((size_t)N * 128 * 4);      // plane layout
  unsigned short* Bbc = (unsigned short*)alloc((size_t)N * 128 * 2);  // plane layout
  unsigned short* Bbo = (unsigned short*)alloc((size_t)N * 128 * 2);  // plane layout
  float*  dis    = (float*)alloc((size_t)N * 4);
  float*  dis2   = (float*)alloc((size_t)N * 4);
  float*  disc   = (float*)alloc((size_t)N * 4);
  float*  diso   = (float*)alloc((size_t)N * 4);
  float*  selfcc = (float*)alloc((size_t)N * 4);
  float*  selfco = (float*)alloc((size_t)N * 4);
  float*  na0    = (float*)alloc((size_t)N * 4);
  float4* PQ     = (float4*)alloc((size_t)N * 16);
  float2* hn     = (float2*)alloc((size_t)N * 8);
  float2* nlog   = (float2*)alloc((size_t)N * 8);
  int*    rs4    = (int*)alloc((size_t)(N + 1) * 4);
  float*  attE   = (float*)alloc((size_t)E * 4);
  int*    edgepos= (int*)alloc((size_t)E * 4);
  int*    wst    = (int*)alloc((size_t)2056 * 4);
  unsigned short* WtAll = (unsigned short*)alloc((size_t)6 * 16384 * 2);
  float*  t1c    = (float*)alloc(512 * 128 * 4);
  float*  t1o    = (float*)alloc(512 * 128 * 4);
  float*  t1co   = (float*)alloc(512 * 128 * 4);

  const int TPB = 256;
  const int NWAVE = 2048;   // waves per pass
  int gE  = (E + TPB - 1) / TPB;
  int gEN = (E + N + TPB - 1) / TPB;
  int gN  = (N + TPB - 1) / TPB;
  int gMM = (N + 63) / 64;

  hipMemsetAsync(zone, 0, zone_bytes, stream);

  // ---- graph structure ----
  k_hist<<<gE, TPB, 0, stream>>>(esrc, edst, E, degF, cnt);
  k_rsqrt1<<<gN, TPB, 0, stream>>>(degF, dis, dis2, N);
  k_scan<<<1, 1024, 0, stream>>>(cnt, N, rs4);
  k_fillB<<<gEN, TPB, 0, stream>>>(esrc, edst, E, N, rs4, cnt, dis, dis2, icP, edgepos);
  k_wstart<<<9, TPB, 0, stream>>>(rs4, N, NWAVE, wst);
  k_prepW6<<<384, TPB, 0, stream>>>(W_feat, convW, xcW, xoW, WtAll);

  // ---- h = relu(BN(x) @ W_feat) -> A planes, fused stats -> statB ----
  k_stats<<<784, TPB, 0, stream>>>(x, N, statA);
  k_finN<<<1, 256, 0, stream>>>(statA, N, statA, N, statA, N);
  k_mm_mfma<1, 0, 1, 0><<<gMM, TPB, 0, stream>>>(x, statA, WtAll, A, N, 0, nullptr, statB);
  k_finN<<<1, 256, 0, stream>>>(statB, N, statB, N, statB, N);

  // ---- 3 GCN layers ----
  for (int l = 0; l < 3; l++) {
    k_mm_mfma<0, 1, 0, 1><<<gMM, TPB, 0, stream>>>(A, statB, WtAll + (size_t)(1 + l) * 16384, Bbc, N, 0, nullptr, nullptr);
    k_gplane<1><<<2048, TPB, 0, stream>>>(Bbc, icP, convB + l * 128, A,
                                          nullptr, nullptr, nullptr, nullptr, nullptr,
                                          rs4, wst, nullptr, N);
    if (l < 2) {
      k_statsP<<<784, TPB, 0, stream>>>(A, N, statB);
      k_finN<<<1, 256, 0, stream>>>(statB, N, statB, N, statB, N);
    }
  }

  // ---- attention ----
  k_pqhnP<<<1024, TPB, 0, stream>>>(A, eW, naW, PQ, hn, N);
  k_natt<<<gN, TPB, 0, stream>>>(hn, rs4, icP, nab, nlog, N);
  k_edge<<<gE, TPB, 0, stream>>>(esrc, edst, E, PQ, eb, attE, degC, degO);
  k_nodefin<<<gN, TPB, 0, stream>>>(degC, degO, nlog, disc, diso, selfcc, selfco, na0, N);
  k_edge2B<<<gEN, TPB, 0, stream>>>(esrc, edst, E, N, attE, edgepos, rs4, disc, diso, selfcc, selfco, icC, icO);

  // ---- xc / xo BN stats ----
  k_stats2P<<<784, TPB, 0, stream>>>(A, N, statA, statB, na0);
  k_finN<<<2, 256, 0, stream>>>(statA, N, statB, N, statB, N);

  // ---- xc / xo matmuls + fused dual weighted gather+pool ----
  k_mm_mfma<0, 1, 0, 1><<<gMM, TPB, 0, stream>>>(A, statA, WtAll + (size_t)4 * 16384, Bbc, N, 1, na0, nullptr);
  k_mm_mfma<0, 1, 0, 1><<<gMM, TPB, 0, stream>>>(A, statB, WtAll + (size_t)5 * 16384, Bbo, N, 2, na0, nullptr);
  k_gplane<2><<<4096, TPB, 0, stream>>>(Bbc, icC, xcb, nullptr,
                                        Bbo, icO, xob, xc_g, xo_g,
                                        rs4, wst, batch, N);

  // ---- heads ----
  k_statsB<<<32, TPB, 0, stream>>>(xc_g, stHC, xo_g, stHO, xo_g, stHO);
  k_finN<<<2, 256, 0, stream>>>(stHC, 512, stHO, 512, stHO, 512);
  k_heads1<<<768, TPB, 0, stream>>>(xc_g, xo_g, stHC, stHO,
                                    cW1, cb1, oW1, ob1, coW1, cob1,
                                    t1c, t1o, t1co);
  k_statsB<<<48, TPB, 0, stream>>>(t1c, st1, t1o, st2, t1co, st3);
  k_finN<<<3, 256, 0, stream>>>(st1, 512, st2, 512, st3, 512);
  k_lsmB<<<6, TPB, 0, stream>>>(t1c, st1, cW2, cb2,
                                t1o, st2, oW2, ob2,
                                t1co, st3, coW2, cob2, out);
}